// Round 9
// baseline (165.943 us; speedup 1.0000x reference)
//
#include <hip/hip_runtime.h>

// Problem sizes (fixed by the reference)
#define NU 100000
#define NI 50000
#define NT 20000
#define DD 128
#define EUI 500000
#define EUT 300000

// ---- NEW bucket space: [items | tags | users(merged rev)] ----
#define B_I   0
#define B_T   (NI)
#define B_U   (NI + NT)                  // merged user buckets
#define NSCAN2 (NI + NT + NU)            // 170000
#define TOTAL_E (2 * (EUI + EUT))        // 1600000

// Legacy bucket space (fallback tiers only)
#define B_UUI (NI + NT)
#define B_UUT (NI + NT + NU)
#define NSCAN (NI + NT + NU + NU)        // 270000

// Counting-sort geometry
#define BPB   512                        // buckets per coarse bin (pow2)
#define NB2   ((NSCAN2 + BPB - 1) / BPB) // 333 coarse bins
#define CH    2048                       // entries per hist/scatter block
#define NBLK  ((TOTAL_E + CH - 1) / CH)  // 782 blocks
#define NT3   111                        // threads covering 333 = 111*3
#define NCVT  ((NU * DD / 8 + 255) / 256) // 3125 cvt blocks

// ---------------------------------------------------------------------------
// bf16 pack/unpack helpers (RNE)
// ---------------------------------------------------------------------------
__device__ __forceinline__ unsigned bfpack(float a, float b) {
    unsigned ua = __float_as_uint(a), ub = __float_as_uint(b);
    ua = (ua + 0x7FFFu + ((ua >> 16) & 1u)) >> 16;
    ub = (ub + 0x7FFFu + ((ub >> 16) & 1u)) >> 16;
    return ua | (ub << 16);
}
__device__ __forceinline__ void bacc(unsigned p, float& a, float& b) {
    a += __uint_as_float(p << 16);
    b += __uint_as_float(p & 0xFFFF0000u);
}

// Non-temporal float4 store (keep streaming outputs out of L2)
typedef float f4_t __attribute__((ext_vector_type(4)));
__device__ __forceinline__ void nts4(float4* p, float x, float y, float z, float w) {
    f4_t v; v.x = x; v.y = y; v.z = z; v.w = w;
    __builtin_nontemporal_store(v, reinterpret_cast<f4_t*>(p));
}

// bucket only (merged space)
__device__ __forceinline__ int bucket_of(int e,
        const int* __restrict__ ui_src, const int* __restrict__ ui_dst,
        const int* __restrict__ ut_src, const int* __restrict__ ut_dst) {
    if (e < EUI)               return B_I + ui_dst[e];
    if (e < 2 * EUI)           return B_U + ui_src[e - EUI];
    if (e < 2 * EUI + EUT)     return B_T + ut_dst[e - 2 * EUI];
    return B_U + ut_src[e - 2 * EUI - EUT];
}

// full entry (merged space). User-bucket values: item idx (<NI) or NI+tag idx.
__device__ __forceinline__ void entry_of(int e,
        const int* __restrict__ ui_src, const int* __restrict__ ui_dst,
        const int* __restrict__ ut_src, const int* __restrict__ ut_dst,
        int& bucket, int& val) {
    if (e < EUI)               { bucket = B_I + ui_dst[e];                 val = ui_src[e]; }
    else if (e < 2 * EUI)      { int j = e - EUI;           bucket = B_U + ui_src[j]; val = ui_dst[j]; }
    else if (e < 2 * EUI + EUT){ int j = e - 2 * EUI;       bucket = B_T + ut_dst[j]; val = ut_src[j]; }
    else                       { int j = e - 2 * EUI - EUT; bucket = B_U + ut_src[j]; val = NI + ut_dst[j]; }
}

// ===========================================================================
// Fused: h_u fp32->bf16 (blocks [0,NCVT)) + coarse histogram (rest).
// ===========================================================================
__global__ void k_cvthist(const float4* __restrict__ in, uint4* __restrict__ out,
                          const int* __restrict__ ui_src, const int* __restrict__ ui_dst,
                          const int* __restrict__ ut_src, const int* __restrict__ ut_dst,
                          int* __restrict__ gbin) {
    __shared__ int h[NB2];
    if (blockIdx.x < NCVT) {
        int t = blockIdx.x * 256 + threadIdx.x;
        if (t < NU * DD / 8) {
            float4 a = in[t * 2 + 0];
            float4 b = in[t * 2 + 1];
            uint4 o;
            o.x = bfpack(a.x, a.y); o.y = bfpack(a.z, a.w);
            o.z = bfpack(b.x, b.y); o.w = bfpack(b.z, b.w);
            out[t] = o;
        }
        return;
    }
    int b = blockIdx.x - NCVT, t = threadIdx.x;
    for (int i = t; i < NB2; i += 256) h[i] = 0;
    __syncthreads();
    int e0 = b * CH;
    int e1 = min(e0 + CH, TOTAL_E);
    for (int e = e0 + t; e < e1; e += 256)
        atomicAdd(&h[bucket_of(e, ui_src, ui_dst, ut_src, ut_dst) >> 9], 1);
    __syncthreads();
    for (int i = t; i < NB2; i += 256)
        if (h[i]) atomicAdd(&gbin[i], h[i]);
}

// ===========================================================================
// Single-block exclusive scan of 333 bin totals -> gstart (+cursor copy)
// ===========================================================================
__global__ void k_scan333(const int* __restrict__ gbin,
                          int* __restrict__ gstart, int* __restrict__ cursor) {
    __shared__ int tsum[256];
    int t = threadIdx.x;
    int i = t * 3;
    int v0 = 0, v1 = 0, v2 = 0;
    if (t < NT3) { v0 = gbin[i]; v1 = gbin[i + 1]; v2 = gbin[i + 2]; }
    int s = v0 + v1 + v2;
    tsum[t] = s;
    __syncthreads();
    for (int o = 1; o < 256; o <<= 1) {
        int x = (t >= o) ? tsum[t - o] : 0;
        __syncthreads();
        tsum[t] += x;
        __syncthreads();
    }
    int base = tsum[t] - s;
    if (t < NT3) {
        gstart[i] = base;                cursor[i] = base;
        gstart[i + 1] = base + v0;       cursor[i + 1] = base + v0;
        gstart[i + 2] = base + v0 + v1;  cursor[i + 2] = base + v0 + v1;
    }
    if (t == 255) gstart[NB2] = tsum[255];
}

// ===========================================================================
// Scatter entries into coarse bins via per-block chunk reservation
// ===========================================================================
__global__ void k_scatterbin2(const int* __restrict__ ui_src, const int* __restrict__ ui_dst,
                              const int* __restrict__ ut_src, const int* __restrict__ ut_dst,
                              int* __restrict__ cursor, unsigned* __restrict__ binned) {
    __shared__ int h[NB2];
    int b = blockIdx.x, t = threadIdx.x;
    for (int i = t; i < NB2; i += 256) h[i] = 0;
    __syncthreads();
    int e0 = b * CH;
    int e1 = min(e0 + CH, TOTAL_E);
    for (int e = e0 + t; e < e1; e += 256)
        atomicAdd(&h[bucket_of(e, ui_src, ui_dst, ut_src, ut_dst) >> 9], 1);
    __syncthreads();
    for (int i = t; i < NB2; i += 256) {
        int c = h[i];
        if (c) h[i] = atomicAdd(&cursor[i], c);   // reserve chunk; h becomes cursor
    }
    __syncthreads();
    for (int e = e0 + t; e < e1; e += 256) {
        int bucket, val;
        entry_of(e, ui_src, ui_dst, ut_src, ut_dst, bucket, val);
        int pos = atomicAdd(&h[bucket >> 9], 1);
        binned[pos] = ((unsigned)(bucket & (BPB - 1)) << 17) | (unsigned)val;
    }
}

// ===========================================================================
// Fused per-bin: count -> LDS scan -> off write -> fine scatter
// ===========================================================================
__global__ void k_fine(const unsigned* __restrict__ binned, const int* __restrict__ gstart,
                       int* __restrict__ off, int* __restrict__ edges) {
    __shared__ int cnt[BPB];
    __shared__ int tsum[256];
    int b = blockIdx.x, t = threadIdx.x;
    cnt[t] = 0; cnt[t + 256] = 0;
    __syncthreads();
    int s = gstart[b], e = gstart[b + 1];
    for (int i = s + t; i < e; i += 256) atomicAdd(&cnt[binned[i] >> 17], 1);
    __syncthreads();
    int v0 = cnt[2 * t], v1 = cnt[2 * t + 1];
    int ps = v0 + v1;
    tsum[t] = ps;
    __syncthreads();
    for (int o = 1; o < 256; o <<= 1) {
        int x = (t >= o) ? tsum[t - o] : 0;
        __syncthreads();
        tsum[t] += x;
        __syncthreads();
    }
    int base = s + tsum[t] - ps;
    int g0 = b * BPB + 2 * t;
    if (g0 < NSCAN2) off[g0] = base;
    if (g0 + 1 < NSCAN2) off[g0 + 1] = base + v0;
    __syncthreads();
    cnt[2 * t] = base;
    cnt[2 * t + 1] = base + v0;
    __syncthreads();
    for (int i = s + t; i < e; i += 256) {
        unsigned v = binned[i];
        int pos = atomicAdd(&cnt[v >> 17], 1);
        edges[pos] = (int)(v & 0x1FFFFu);
    }
}

// ===========================================================================
// Gather core: 16 lanes/row, uint4 (8 bf16) per lane, 8-wide load batching.
// ===========================================================================
__device__ __forceinline__ void gacc16(const uint4* __restrict__ feat,
                                       const int* __restrict__ edges,
                                       int start, int end, int c,
                                       float& a0, float& a1, float& a2, float& a3,
                                       float& a4, float& a5, float& a6, float& a7) {
    for (int base = start; base < end; base += 16) {
        int n = end - base; if (n > 16) n = 16;
        int eidx = (c < n) ? edges[base + c] : 0;
        int k = 0;
        for (; k + 8 <= n; k += 8) {
            int s0 = __shfl(eidx, k + 0, 16), s1 = __shfl(eidx, k + 1, 16);
            int s2 = __shfl(eidx, k + 2, 16), s3 = __shfl(eidx, k + 3, 16);
            int s4 = __shfl(eidx, k + 4, 16), s5 = __shfl(eidx, k + 5, 16);
            int s6 = __shfl(eidx, k + 6, 16), s7 = __shfl(eidx, k + 7, 16);
            uint4 p0 = feat[(size_t)s0 * 16 + c], p1 = feat[(size_t)s1 * 16 + c];
            uint4 p2 = feat[(size_t)s2 * 16 + c], p3 = feat[(size_t)s3 * 16 + c];
            uint4 p4 = feat[(size_t)s4 * 16 + c], p5 = feat[(size_t)s5 * 16 + c];
            uint4 p6 = feat[(size_t)s6 * 16 + c], p7 = feat[(size_t)s7 * 16 + c];
            bacc(p0.x, a0, a1); bacc(p0.y, a2, a3); bacc(p0.z, a4, a5); bacc(p0.w, a6, a7);
            bacc(p1.x, a0, a1); bacc(p1.y, a2, a3); bacc(p1.z, a4, a5); bacc(p1.w, a6, a7);
            bacc(p2.x, a0, a1); bacc(p2.y, a2, a3); bacc(p2.z, a4, a5); bacc(p2.w, a6, a7);
            bacc(p3.x, a0, a1); bacc(p3.y, a2, a3); bacc(p3.z, a4, a5); bacc(p3.w, a6, a7);
            bacc(p4.x, a0, a1); bacc(p4.y, a2, a3); bacc(p4.z, a4, a5); bacc(p4.w, a6, a7);
            bacc(p5.x, a0, a1); bacc(p5.y, a2, a3); bacc(p5.z, a4, a5); bacc(p5.w, a6, a7);
            bacc(p6.x, a0, a1); bacc(p6.y, a2, a3); bacc(p6.z, a4, a5); bacc(p6.w, a6, a7);
            bacc(p7.x, a0, a1); bacc(p7.y, a2, a3); bacc(p7.z, a4, a5); bacc(p7.w, a6, a7);
        }
        for (; k + 2 <= n; k += 2) {
            int s0 = __shfl(eidx, k + 0, 16), s1 = __shfl(eidx, k + 1, 16);
            uint4 p0 = feat[(size_t)s0 * 16 + c], p1 = feat[(size_t)s1 * 16 + c];
            bacc(p0.x, a0, a1); bacc(p0.y, a2, a3); bacc(p0.z, a4, a5); bacc(p0.w, a6, a7);
            bacc(p1.x, a0, a1); bacc(p1.y, a2, a3); bacc(p1.z, a4, a5); bacc(p1.w, a6, a7);
        }
        if (k < n) {
            int s0 = __shfl(eidx, k, 16);
            uint4 p0 = feat[(size_t)s0 * 16 + c];
            bacc(p0.x, a0, a1); bacc(p0.y, a2, a3); bacc(p0.z, a4, a5); bacc(p0.w, a6, a7);
        }
    }
}

// Merged forward gather over items [0,NI) + tags [NI,NI+NT); bucket id == row.
__global__ void g_fwd(const uint4* __restrict__ feat,
                      const int* __restrict__ off, const int* __restrict__ edges,
                      uint4* __restrict__ rsti_b, uint4* __restrict__ rstt_b,
                      float4* __restrict__ outf) {
    int tid = blockIdx.x * blockDim.x + threadIdx.x;
    int r = tid >> 4;
    int c = tid & 15;
    if (r >= NI + NT) return;
    int start = off[r];
    int end = off[r + 1];
    float a0=0.f,a1=0.f,a2=0.f,a3=0.f,a4=0.f,a5=0.f,a6=0.f,a7=0.f;
    gacc16(feat, edges, start, end, c, a0, a1, a2, a3, a4, a5, a6, a7);
    float inv = 1.0f / fmaxf((float)(end - start), 1.0f);
    a0*=inv; a1*=inv; a2*=inv; a3*=inv; a4*=inv; a5*=inv; a6*=inv; a7*=inv;
    uint4 ob;
    ob.x = bfpack(a0,a1); ob.y = bfpack(a2,a3);
    ob.z = bfpack(a4,a5); ob.w = bfpack(a6,a7);
    if (r < NI) {
        rsti_b[(size_t)r * 16 + c] = ob;
    } else {
        int rt = r - NI;
        rstt_b[(size_t)rt * 16 + c] = ob;
        nts4(&outf[(size_t)rt * 32 + c*2 + 0], a0, a1, a2, a3);
        nts4(&outf[(size_t)rt * 32 + c*2 + 1], a4, a5, a6, a7);
    }
}

// Backward gather: ONE merged user bucket, unified rst table (rows [0,NI)=items,
// [NI,NI+NT)=tags, contiguous). Per-etype degree via ballot count of val<NI.
__global__ void g_bwd(const uint4* __restrict__ rst,
                      const int* __restrict__ off, const int* __restrict__ edges,
                      float4* __restrict__ bsrc) {
    int tid = blockIdx.x * blockDim.x + threadIdx.x;
    int r = tid >> 4;
    int c = tid & 15;
    if (r >= NU) return;
    int g = B_U + r;
    int s = off[g];
    int e = (g + 1 < NSCAN2) ? off[g + 1] : TOTAL_E;
    int gsh = threadIdx.x & 48;   // group's bit offset within the 64-lane ballot
    int nui = 0;
    float a0=0.f,a1=0.f,a2=0.f,a3=0.f,a4=0.f,a5=0.f,a6=0.f,a7=0.f;
    for (int base = s; base < e; base += 16) {
        int n = e - base; if (n > 16) n = 16;
        int eidx = (c < n) ? edges[base + c] : 0x7FFFFFFF;
        unsigned long long m = __ballot((c < n) && (eidx < NI));
        nui += (int)__popcll((m >> gsh) & 0xFFFFull);
        int k = 0;
        for (; k + 8 <= n; k += 8) {
            int s0 = __shfl(eidx, k + 0, 16), s1 = __shfl(eidx, k + 1, 16);
            int s2 = __shfl(eidx, k + 2, 16), s3 = __shfl(eidx, k + 3, 16);
            int s4 = __shfl(eidx, k + 4, 16), s5 = __shfl(eidx, k + 5, 16);
            int s6 = __shfl(eidx, k + 6, 16), s7 = __shfl(eidx, k + 7, 16);
            uint4 p0 = rst[(size_t)s0 * 16 + c], p1 = rst[(size_t)s1 * 16 + c];
            uint4 p2 = rst[(size_t)s2 * 16 + c], p3 = rst[(size_t)s3 * 16 + c];
            uint4 p4 = rst[(size_t)s4 * 16 + c], p5 = rst[(size_t)s5 * 16 + c];
            uint4 p6 = rst[(size_t)s6 * 16 + c], p7 = rst[(size_t)s7 * 16 + c];
            bacc(p0.x, a0, a1); bacc(p0.y, a2, a3); bacc(p0.z, a4, a5); bacc(p0.w, a6, a7);
            bacc(p1.x, a0, a1); bacc(p1.y, a2, a3); bacc(p1.z, a4, a5); bacc(p1.w, a6, a7);
            bacc(p2.x, a0, a1); bacc(p2.y, a2, a3); bacc(p2.z, a4, a5); bacc(p2.w, a6, a7);
            bacc(p3.x, a0, a1); bacc(p3.y, a2, a3); bacc(p3.z, a4, a5); bacc(p3.w, a6, a7);
            bacc(p4.x, a0, a1); bacc(p4.y, a2, a3); bacc(p4.z, a4, a5); bacc(p4.w, a6, a7);
            bacc(p5.x, a0, a1); bacc(p5.y, a2, a3); bacc(p5.z, a4, a5); bacc(p5.w, a6, a7);
            bacc(p6.x, a0, a1); bacc(p6.y, a2, a3); bacc(p6.z, a4, a5); bacc(p6.w, a6, a7);
            bacc(p7.x, a0, a1); bacc(p7.y, a2, a3); bacc(p7.z, a4, a5); bacc(p7.w, a6, a7);
        }
        for (; k + 2 <= n; k += 2) {
            int s0 = __shfl(eidx, k + 0, 16), s1 = __shfl(eidx, k + 1, 16);
            uint4 p0 = rst[(size_t)s0 * 16 + c], p1 = rst[(size_t)s1 * 16 + c];
            bacc(p0.x, a0, a1); bacc(p0.y, a2, a3); bacc(p0.z, a4, a5); bacc(p0.w, a6, a7);
            bacc(p1.x, a0, a1); bacc(p1.y, a2, a3); bacc(p1.z, a4, a5); bacc(p1.w, a6, a7);
        }
        if (k < n) {
            int s0 = __shfl(eidx, k, 16);
            uint4 p0 = rst[(size_t)s0 * 16 + c];
            bacc(p0.x, a0, a1); bacc(p0.y, a2, a3); bacc(p0.z, a4, a5); bacc(p0.w, a6, a7);
        }
    }
    int ntot = e - s;
    float denom = fmaxf((float)nui, 1.0f) + fmaxf((float)(ntot - nui), 1.0f);
    float inv = 1.0f / denom;
    nts4(&bsrc[(size_t)r * 32 + c*2 + 0], a0*inv, a1*inv, a2*inv, a3*inv);
    nts4(&bsrc[(size_t)r * 32 + c*2 + 1], a4*inv, a5*inv, a6*inv, a7*inv);
}

// ===========================================================================
// Legacy kernels for fallback tiers (old bucket space, unchanged)
// ===========================================================================
__global__ void k_scanA(int* __restrict__ data, int* __restrict__ bsums, int n) {
    __shared__ int lds[256];
    int b = blockIdx.x, t = threadIdx.x;
    int base = b * 1024 + t * 4;
    int v0 = (base + 0 < n) ? data[base + 0] : 0;
    int v1 = (base + 1 < n) ? data[base + 1] : 0;
    int v2 = (base + 2 < n) ? data[base + 2] : 0;
    int v3 = (base + 3 < n) ? data[base + 3] : 0;
    int i0 = v0, i1 = i0 + v1, i2 = i1 + v2, i3 = i2 + v3;
    lds[t] = i3;
    __syncthreads();
    for (int o = 1; o < 256; o <<= 1) {
        int x = (t >= o) ? lds[t - o] : 0;
        __syncthreads();
        lds[t] += x;
        __syncthreads();
    }
    int ex = lds[t] - i3;
    if (base + 0 < n) data[base + 0] = ex + i0;
    if (base + 1 < n) data[base + 1] = ex + i1;
    if (base + 2 < n) data[base + 2] = ex + i2;
    if (base + 3 < n) data[base + 3] = ex + i3;
    if (t == 255) bsums[b] = lds[255];
}

__global__ void k_scanB(int* __restrict__ bsums, int nsb) {
    __shared__ int lds[512];
    int t = threadIdx.x;
    int a = (t < nsb) ? bsums[t] : 0;
    int b2 = (t + 256 < nsb) ? bsums[t + 256] : 0;
    lds[t] = a;
    lds[t + 256] = b2;
    __syncthreads();
    for (int o = 1; o < 512; o <<= 1) {
        int x0 = (t >= o) ? lds[t - o] : 0;
        int x1 = (t + 256 >= o) ? lds[t + 256 - o] : 0;
        __syncthreads();
        lds[t] += x0;
        lds[t + 256] += x1;
        __syncthreads();
    }
    if (t < nsb) bsums[t] = lds[t] - a;
    if (t + 256 < nsb) bsums[t + 256] = lds[t + 256] - b2;
}

__global__ void k_scanC(int* __restrict__ data, const int* __restrict__ bsums, int n) {
    int b = blockIdx.x;
    int add = bsums[b];
    int base = b * 1024 + threadIdx.x * 4;
    if (base + 0 < n) data[base + 0] += add;
    if (base + 1 < n) data[base + 1] += add;
    if (base + 2 < n) data[base + 2] += add;
    if (base + 3 < n) data[base + 3] += add;
}

__global__ void k_count_old(const int4* __restrict__ ui_src, const int4* __restrict__ ui_dst,
                            const int4* __restrict__ ut_src, const int4* __restrict__ ut_dst,
                            int* __restrict__ off) {
    int i = blockIdx.x * blockDim.x + threadIdx.x;
    if (i < EUI / 4) {
        int4 s = ui_src[i], d = ui_dst[i];
        atomicAdd(&off[B_I + d.x], 1); atomicAdd(&off[B_I + d.y], 1);
        atomicAdd(&off[B_I + d.z], 1); atomicAdd(&off[B_I + d.w], 1);
        atomicAdd(&off[B_UUI + s.x], 1); atomicAdd(&off[B_UUI + s.y], 1);
        atomicAdd(&off[B_UUI + s.z], 1); atomicAdd(&off[B_UUI + s.w], 1);
    } else if (i < EUI / 4 + EUT / 4) {
        int j = i - EUI / 4;
        int4 s = ut_src[j], d = ut_dst[j];
        atomicAdd(&off[B_T + d.x], 1); atomicAdd(&off[B_T + d.y], 1);
        atomicAdd(&off[B_T + d.z], 1); atomicAdd(&off[B_T + d.w], 1);
        atomicAdd(&off[B_UUT + s.x], 1); atomicAdd(&off[B_UUT + s.y], 1);
        atomicAdd(&off[B_UUT + s.z], 1); atomicAdd(&off[B_UUT + s.w], 1);
    }
}

__global__ void k_fill_old(const int2* __restrict__ ui_src, const int2* __restrict__ ui_dst,
                           const int2* __restrict__ ut_src, const int2* __restrict__ ut_dst,
                           int* __restrict__ off, int* __restrict__ edges) {
    int i = blockIdx.x * blockDim.x + threadIdx.x;
    if (i < EUI / 2) {
        int2 s = ui_src[i], d = ui_dst[i];
        edges[atomicAdd(&off[B_I + d.x], -1) - 1] = s.x;
        edges[atomicAdd(&off[B_UUI + s.x], -1) - 1] = d.x;
        edges[atomicAdd(&off[B_I + d.y], -1) - 1] = s.y;
        edges[atomicAdd(&off[B_UUI + s.y], -1) - 1] = d.y;
    } else if (i < EUI / 2 + EUT / 2) {
        int j = i - EUI / 2;
        int2 s = ut_src[j], d = ut_dst[j];
        edges[atomicAdd(&off[B_T + d.x], -1) - 1] = s.x;
        edges[atomicAdd(&off[B_UUT + s.x], -1) - 1] = d.x;
        edges[atomicAdd(&off[B_T + d.y], -1) - 1] = s.y;
        edges[atomicAdd(&off[B_UUT + s.y], -1) - 1] = d.y;
    }
}

__global__ void k_gather_fwd_f(const float4* __restrict__ feat,
                               const int* __restrict__ off, const int* __restrict__ edges,
                               uint2* __restrict__ outb, float4* __restrict__ outf,
                               int base, int nrows) {
    int tid = blockIdx.x * blockDim.x + threadIdx.x;
    int r = tid >> 5;
    int c = tid & 31;
    if (r >= nrows) return;
    int g = base + r;
    int start = off[g];
    int end = (g + 1 < NSCAN) ? off[g + 1] : TOTAL_E;
    float a0 = 0.f, a1 = 0.f, a2 = 0.f, a3 = 0.f;
    for (int e = start; e < end; ++e) {
        float4 v = feat[(size_t)edges[e] * 32 + c];
        a0 += v.x; a1 += v.y; a2 += v.z; a3 += v.w;
    }
    float inv = 1.0f / fmaxf((float)(end - start), 1.0f);
    a0 *= inv; a1 *= inv; a2 *= inv; a3 *= inv;
    uint2 ob; ob.x = bfpack(a0, a1); ob.y = bfpack(a2, a3);
    outb[(size_t)r * 32 + c] = ob;
    if (outf) {
        float4 of; of.x = a0; of.y = a1; of.z = a2; of.w = a3;
        outf[(size_t)r * 32 + c] = of;
    }
}

__global__ void k_gather_bwd_b(const uint2* __restrict__ rst_i,
                               const uint2* __restrict__ rst_t,
                               const int* __restrict__ off, const int* __restrict__ edges,
                               float4* __restrict__ bsrc) {
    int tid = blockIdx.x * blockDim.x + threadIdx.x;
    int r = tid >> 5;
    int c = tid & 31;
    if (r >= NU) return;
    int g1 = B_UUI + r;
    int s1 = off[g1], e1 = off[g1 + 1];
    int g2 = B_UUT + r;
    int s2 = off[g2], e2 = (g2 + 1 < NSCAN) ? off[g2 + 1] : TOTAL_E;
    float a0 = 0.f, a1 = 0.f, a2 = 0.f, a3 = 0.f;
    for (int e = s1; e < e1; ++e) {
        uint2 p = rst_i[(size_t)edges[e] * 32 + c];
        bacc(p.x, a0, a1); bacc(p.y, a2, a3);
    }
    for (int e = s2; e < e2; ++e) {
        uint2 p = rst_t[(size_t)edges[e] * 32 + c];
        bacc(p.x, a0, a1); bacc(p.y, a2, a3);
    }
    float inv = 1.0f / (fmaxf((float)(e1 - s1), 1.0f) + fmaxf((float)(e2 - s2), 1.0f));
    float4 o;
    o.x = a0 * inv; o.y = a1 * inv; o.z = a2 * inv; o.w = a3 * inv;
    bsrc[(size_t)r * 32 + c] = o;
}

__global__ void f_count(const int* __restrict__ ui_src, const int* __restrict__ ui_dst,
                        const int* __restrict__ ut_src, const int* __restrict__ ut_dst,
                        float* __restrict__ cnt_uui, float* __restrict__ cnt_i,
                        float* __restrict__ cnt_uut, float* __restrict__ cnt_t) {
    int i = blockIdx.x * blockDim.x + threadIdx.x;
    if (i < EUI) {
        unsafeAtomicAdd(&cnt_uui[ui_src[i]], 1.0f);
        unsafeAtomicAdd(&cnt_i[ui_dst[i]], 1.0f);
    } else if (i < EUI + EUT) {
        int j = i - EUI;
        unsafeAtomicAdd(&cnt_uut[ut_src[j]], 1.0f);
        unsafeAtomicAdd(&cnt_t[ut_dst[j]], 1.0f);
    }
}
__global__ void f_scatter_fwd(const float4* __restrict__ feat, const int* __restrict__ src,
                              const int* __restrict__ dst, float* __restrict__ out_sum, int nedge) {
    int tid = blockIdx.x * blockDim.x + threadIdx.x;
    int e = tid >> 5, c = tid & 31;
    if (e >= nedge) return;
    float4 v = feat[(size_t)src[e] * 32 + c];
    float* o = out_sum + (size_t)dst[e] * DD + c * 4;
    unsafeAtomicAdd(o + 0, v.x); unsafeAtomicAdd(o + 1, v.y);
    unsafeAtomicAdd(o + 2, v.z); unsafeAtomicAdd(o + 3, v.w);
}
__global__ void f_scatter_bwd(const float4* __restrict__ rst_sum, const float* __restrict__ cnt,
                              const int* __restrict__ src, const int* __restrict__ dst,
                              float* __restrict__ bsrc, int nedge) {
    int tid = blockIdx.x * blockDim.x + threadIdx.x;
    int e = tid >> 5, c = tid & 31;
    if (e >= nedge) return;
    float inv = 1.0f / fmaxf(cnt[dst[e]], 1.0f);
    float4 v = rst_sum[(size_t)dst[e] * 32 + c];
    float* o = bsrc + (size_t)src[e] * DD + c * 4;
    unsafeAtomicAdd(o + 0, v.x * inv); unsafeAtomicAdd(o + 1, v.y * inv);
    unsafeAtomicAdd(o + 2, v.z * inv); unsafeAtomicAdd(o + 3, v.w * inv);
}
__global__ void f_norm(float4* __restrict__ rst, const float* __restrict__ cnt, int nrows) {
    int tid = blockIdx.x * blockDim.x + threadIdx.x;
    int r = tid >> 5, c = tid & 31;
    if (r >= nrows) return;
    float inv = 1.0f / fmaxf(cnt[r], 1.0f);
    float4 v = rst[(size_t)r * 32 + c];
    v.x *= inv; v.y *= inv; v.z *= inv; v.w *= inv;
    rst[(size_t)r * 32 + c] = v;
}
__global__ void f_final(float4* __restrict__ bsrc, const float* __restrict__ cnt_a,
                        const float* __restrict__ cnt_b, int nrows) {
    int tid = blockIdx.x * blockDim.x + threadIdx.x;
    int r = tid >> 5, c = tid & 31;
    if (r >= nrows) return;
    float inv = 1.0f / (fmaxf(cnt_a[r], 1.0f) + fmaxf(cnt_b[r], 1.0f));
    float4 v = bsrc[(size_t)r * 32 + c];
    v.x *= inv; v.y *= inv; v.z *= inv; v.w *= inv;
    bsrc[(size_t)r * 32 + c] = v;
}

// ===========================================================================

extern "C" void kernel_launch(void* const* d_in, const int* in_sizes, int n_in,
                              void* d_out, int out_size, void* d_ws, size_t ws_size,
                              hipStream_t stream) {
    const float* h_u  = (const float*)d_in[0];
    const int* ui_src = (const int*)d_in[3];
    const int* ui_dst = (const int*)d_in[4];
    const int* ut_src = (const int*)d_in[5];
    const int* ut_dst = (const int*)d_in[6];

    float* bsrc  = (float*)d_out;                       // [NU*DD]
    float* rst_t = (float*)d_out + (size_t)NU * DD;     // [NT*DD]

    const int B = 256;

    // Workspace layout (NEED_FULL identical to rounds 2-8 -> proven available):
    //   ints : off[NSCAN] | bsums[512] | edges[TOTAL_E]           = 7,482,048 B
    //   bf16 : hu_b[NU*DD] | rsti_b[NI*DD] | rstt_b[NT*DD]        = 43,520,000 B
    // rsti_b and rstt_b are CONTIGUOUS -> unified rst table for g_bwd.
    // Aliases (dead before their region is written by the gathers):
    //   binned (TOTAL_E u32 = 6.4 MB)            @ rsti_b region
    //   gbin[333]|gstart[334]|cursor[333] ints   @ rstt_b region
    const size_t INT_WORDS = (size_t)NSCAN + 512 + TOTAL_E;    // 1,870,512
    const size_t BASE_B    = INT_WORDS * 4;                    // 7,482,048 (16B-aligned)
    const size_t HUB_B     = (size_t)NU * DD * 2;              // 25,600,000
    const size_t RIB_B     = (size_t)NI * DD * 2;              // 12,800,000
    const size_t RTB_B     = (size_t)NT * DD * 2;              //  5,120,000
    const size_t NEED_FULL = BASE_B + HUB_B + RIB_B + RTB_B;   // 51,002,048
    const size_t NEED_HALF = BASE_B + RIB_B + RTB_B;           // ~25.4 MB

    if (ws_size >= NEED_FULL) {
        int* off      = (int*)d_ws;
        int* bsums    = off + NSCAN;   (void)bsums;
        int* edges    = bsums + 512;
        uint4* hu_b   = (uint4*)((char*)d_ws + BASE_B);
        uint4* rsti_b = (uint4*)((char*)d_ws + BASE_B + HUB_B);
        uint4* rstt_b = (uint4*)((char*)d_ws + BASE_B + HUB_B + RIB_B);
        unsigned* binned = (unsigned*)rsti_b;        // alias, dead before g_fwd writes
        int* gbin   = (int*)rstt_b;                  // alias, dead before g_fwd writes
        int* gstart = gbin + NB2;                    // [NB2+1]
        int* cursor = gstart + NB2 + 1;              // [NB2]

        // 0. zero the 333 coarse-bin counters
        hipMemsetAsync(gbin, 0, NB2 * sizeof(int), stream);

        // 1. fused cvt (3125 blocks) + coarse histogram (782 blocks)
        k_cvthist<<<NCVT + NBLK, B, 0, stream>>>(
            (const float4*)h_u, hu_b, ui_src, ui_dst, ut_src, ut_dst, gbin);

        // 2. single-block scan of 333 -> gstart / cursor
        k_scan333<<<1, B, 0, stream>>>(gbin, gstart, cursor);

        // 3. scatter entries into coarse bins (per-block chunk reservation)
        k_scatterbin2<<<NBLK, B, 0, stream>>>(ui_src, ui_dst, ut_src, ut_dst, cursor, binned);

        // 4. fused per-bin count + LDS scan + off write + fine scatter
        k_fine<<<NB2, B, 0, stream>>>(binned, gstart, off, edges);

        // 5. merged forward gather (items + tags), then merged backward gather
        g_fwd<<<((long)(NI + NT) * 16 + B - 1) / B, B, 0, stream>>>(
            hu_b, off, edges, rsti_b, rstt_b, (float4*)rst_t);
        g_bwd<<<((long)NU * 16 + B - 1) / B, B, 0, stream>>>(
            rsti_b /* unified table: items then tags */, off, edges, (float4*)bsrc);
    } else if (ws_size >= NEED_HALF) {
        int* off   = (int*)d_ws;
        int* bsums = off + NSCAN;
        int* edges = bsums + 512;
        uint2* rsti_b = (uint2*)((char*)d_ws + BASE_B);
        uint2* rstt_b = (uint2*)((char*)d_ws + BASE_B + RIB_B);

        hipMemsetAsync(off, 0, (NSCAN + 512) * sizeof(int), stream);

        int nq = EUI / 4 + EUT / 4;
        k_count_old<<<(nq + B - 1) / B, B, 0, stream>>>(
            (const int4*)ui_src, (const int4*)ui_dst,
            (const int4*)ut_src, (const int4*)ut_dst, off);
        {
            int nblk = (NSCAN + 1023) / 1024;
            k_scanA<<<nblk, B, 0, stream>>>(off, bsums, NSCAN);
            k_scanB<<<1, B, 0, stream>>>(bsums, nblk);
            k_scanC<<<nblk, B, 0, stream>>>(off, bsums, NSCAN);
        }
        int nh = EUI / 2 + EUT / 2;
        k_fill_old<<<(nh + B - 1) / B, B, 0, stream>>>(
            (const int2*)ui_src, (const int2*)ui_dst,
            (const int2*)ut_src, (const int2*)ut_dst, off, edges);

        k_gather_fwd_f<<<((long)NI * 32 + B - 1) / B, B, 0, stream>>>(
            (const float4*)h_u, off, edges, rsti_b, (float4*)nullptr, B_I, NI);
        k_gather_fwd_f<<<((long)NT * 32 + B - 1) / B, B, 0, stream>>>(
            (const float4*)h_u, off, edges, rstt_b, (float4*)rst_t, B_T, NT);
        k_gather_bwd_b<<<((long)NU * 32 + B - 1) / B, B, 0, stream>>>(
            rsti_b, rstt_b, off, edges, (float4*)bsrc);
    } else {
        // Atomic fallback (~26.7 MB ws).
        float* ws        = (float*)d_ws;
        float* rst_i_sum = ws;
        float* cnt_i     = rst_i_sum + (size_t)NI * DD;
        float* cnt_t     = cnt_i + NI;
        float* cnt_uui   = cnt_t + NT;
        float* cnt_uut   = cnt_uui + NU;
        size_t ws_floats = (size_t)NI * DD + NI + NT + NU + NU;

        hipMemsetAsync(d_ws, 0, ws_floats * sizeof(float), stream);
        hipMemsetAsync(d_out, 0, (size_t)out_size * sizeof(float), stream);

        int n = EUI + EUT;
        f_count<<<(n + B - 1) / B, B, 0, stream>>>(ui_src, ui_dst, ut_src, ut_dst,
                                                   cnt_uui, cnt_i, cnt_uut, cnt_t);
        f_scatter_fwd<<<((long)EUI * 32 + B - 1) / B, B, 0, stream>>>(
            (const float4*)h_u, ui_src, ui_dst, rst_i_sum, EUI);
        f_scatter_fwd<<<((long)EUT * 32 + B - 1) / B, B, 0, stream>>>(
            (const float4*)h_u, ut_src, ut_dst, rst_t, EUT);
        f_scatter_bwd<<<((long)EUI * 32 + B - 1) / B, B, 0, stream>>>(
            (const float4*)rst_i_sum, cnt_i, ui_src, ui_dst, bsrc, EUI);
        f_scatter_bwd<<<((long)EUT * 32 + B - 1) / B, B, 0, stream>>>(
            (const float4*)rst_t, cnt_t, ut_src, ut_dst, bsrc, EUT);
        f_norm<<<((long)NT * 32 + B - 1) / B, B, 0, stream>>>((float4*)rst_t, cnt_t, NT);
        f_final<<<((long)NU * 32 + B - 1) / B, B, 0, stream>>>((float4*)bsrc, cnt_uui, cnt_uut, NU);
    }
}

// Round 10
// 159.481 us; speedup vs baseline: 1.0405x; 1.0405x over previous
//
#include <hip/hip_runtime.h>

// Problem sizes (fixed by the reference)
#define NU 100000
#define NI 50000
#define NT 20000
#define DD 128
#define EUI 500000
#define EUT 300000

// Concatenated bucket space: [items | tags | users(ui-rev) | users(ut-rev)]
#define B_I   0
#define B_T   (NI)
#define B_UUI (NI + NT)
#define B_UUT (NI + NT + NU)
#define NSCAN (NI + NT + NU + NU)       // 270000
#define TOTAL_E (2 * (EUI + EUT))       // 1600000

// Counting-sort geometry
#define BPB   512                        // buckets per coarse bin (pow2)
#define NB    ((NSCAN + BPB - 1) / BPB)  // 528 coarse bins
#define CH    2048                       // entries per hist/scatter block
#define NBLK  ((TOTAL_E + CH - 1) / CH)  // 782 blocks
#define NT3   176                        // threads covering 528 = 176*3
#define NCVT  ((NU * DD / 8 + 255) / 256) // 3125 cvt blocks

// ---------------------------------------------------------------------------
// bf16 pack/unpack helpers (RNE)
// ---------------------------------------------------------------------------
__device__ __forceinline__ unsigned bfpack(float a, float b) {
    unsigned ua = __float_as_uint(a), ub = __float_as_uint(b);
    ua = (ua + 0x7FFFu + ((ua >> 16) & 1u)) >> 16;
    ub = (ub + 0x7FFFu + ((ub >> 16) & 1u)) >> 16;
    return ua | (ub << 16);
}
__device__ __forceinline__ void bacc(unsigned p, float& a, float& b) {
    a += __uint_as_float(p << 16);
    b += __uint_as_float(p & 0xFFFF0000u);
}

// Non-temporal float4 store (keep streaming outputs out of L2)
typedef float f4_t __attribute__((ext_vector_type(4)));
__device__ __forceinline__ void nts4(float4* p, float x, float y, float z, float w) {
    f4_t v; v.x = x; v.y = y; v.z = z; v.w = w;
    __builtin_nontemporal_store(v, reinterpret_cast<f4_t*>(p));
}

// bucket only
__device__ __forceinline__ int bucket_of(int e,
        const int* __restrict__ ui_src, const int* __restrict__ ui_dst,
        const int* __restrict__ ut_src, const int* __restrict__ ut_dst) {
    if (e < EUI)               return B_I   + ui_dst[e];
    if (e < 2 * EUI)           return B_UUI + ui_src[e - EUI];
    if (e < 2 * EUI + EUT)     return B_T   + ut_dst[e - 2 * EUI];
    return B_UUT + ut_src[e - 2 * EUI - EUT];
}

// full entry
__device__ __forceinline__ void entry_of(int e,
        const int* __restrict__ ui_src, const int* __restrict__ ui_dst,
        const int* __restrict__ ut_src, const int* __restrict__ ut_dst,
        int& bucket, int& val) {
    if (e < EUI)               { bucket = B_I   + ui_dst[e];               val = ui_src[e]; }
    else if (e < 2 * EUI)      { int j = e - EUI;           bucket = B_UUI + ui_src[j]; val = ui_dst[j]; }
    else if (e < 2 * EUI + EUT){ int j = e - 2 * EUI;       bucket = B_T   + ut_dst[j]; val = ut_src[j]; }
    else                       { int j = e - 2 * EUI - EUT; bucket = B_UUT + ut_src[j]; val = ut_dst[j]; }
}

// ===========================================================================
// Fused: h_u fp32->bf16 (blocks [0,NCVT)) + coarse histogram (rest).
// Independent phases — overlap BW-bound cvt with latency-bound hist.
// ===========================================================================
__global__ void k_cvthist(const float4* __restrict__ in, uint4* __restrict__ out,
                          const int* __restrict__ ui_src, const int* __restrict__ ui_dst,
                          const int* __restrict__ ut_src, const int* __restrict__ ut_dst,
                          int* __restrict__ gbin) {
    __shared__ int h[NB];
    if (blockIdx.x < NCVT) {
        int t = blockIdx.x * 256 + threadIdx.x;
        if (t < NU * DD / 8) {
            float4 a = in[t * 2 + 0];
            float4 b = in[t * 2 + 1];
            uint4 o;
            o.x = bfpack(a.x, a.y); o.y = bfpack(a.z, a.w);
            o.z = bfpack(b.x, b.y); o.w = bfpack(b.z, b.w);
            out[t] = o;
        }
        return;
    }
    int b = blockIdx.x - NCVT, t = threadIdx.x;
    for (int i = t; i < NB; i += 256) h[i] = 0;
    __syncthreads();
    int e0 = b * CH;
    int e1 = min(e0 + CH, TOTAL_E);
    for (int e = e0 + t; e < e1; e += 256)
        atomicAdd(&h[bucket_of(e, ui_src, ui_dst, ut_src, ut_dst) >> 9], 1);
    __syncthreads();
    for (int i = t; i < NB; i += 256)
        if (h[i]) atomicAdd(&gbin[i], h[i]);
}

// ===========================================================================
// Single-block exclusive scan of 528 bin totals -> gstart (+cursor copy)
// ===========================================================================
__global__ void k_scan528(const int* __restrict__ gbin,
                          int* __restrict__ gstart, int* __restrict__ cursor) {
    __shared__ int tsum[256];
    int t = threadIdx.x;
    int i = t * 3;
    int v0 = 0, v1 = 0, v2 = 0;
    if (t < NT3) { v0 = gbin[i]; v1 = gbin[i + 1]; v2 = gbin[i + 2]; }
    int s = v0 + v1 + v2;
    tsum[t] = s;
    __syncthreads();
    for (int o = 1; o < 256; o <<= 1) {
        int x = (t >= o) ? tsum[t - o] : 0;
        __syncthreads();
        tsum[t] += x;
        __syncthreads();
    }
    int base = tsum[t] - s;
    if (t < NT3) {
        gstart[i] = base;                cursor[i] = base;
        gstart[i + 1] = base + v0;       cursor[i + 1] = base + v0;
        gstart[i + 2] = base + v0 + v1;  cursor[i + 2] = base + v0 + v1;
    }
    if (t == 255) gstart[NB] = tsum[255];
}

// ===========================================================================
// Scatter entries into coarse bins via per-block chunk reservation
// ===========================================================================
__global__ void k_scatterbin2(const int* __restrict__ ui_src, const int* __restrict__ ui_dst,
                              const int* __restrict__ ut_src, const int* __restrict__ ut_dst,
                              int* __restrict__ cursor, unsigned* __restrict__ binned) {
    __shared__ int h[NB];
    int b = blockIdx.x, t = threadIdx.x;
    for (int i = t; i < NB; i += 256) h[i] = 0;
    __syncthreads();
    int e0 = b * CH;
    int e1 = min(e0 + CH, TOTAL_E);
    for (int e = e0 + t; e < e1; e += 256)
        atomicAdd(&h[bucket_of(e, ui_src, ui_dst, ut_src, ut_dst) >> 9], 1);
    __syncthreads();
    for (int i = t; i < NB; i += 256) {
        int c = h[i];
        if (c) h[i] = atomicAdd(&cursor[i], c);   // reserve chunk; h becomes cursor
    }
    __syncthreads();
    for (int e = e0 + t; e < e1; e += 256) {
        int bucket, val;
        entry_of(e, ui_src, ui_dst, ut_src, ut_dst, bucket, val);
        int pos = atomicAdd(&h[bucket >> 9], 1);
        binned[pos] = ((unsigned)(bucket & (BPB - 1)) << 17) | (unsigned)val;
    }
}

// ===========================================================================
// Fused per-bin: count -> LDS scan -> off write -> fine scatter
// ===========================================================================
__global__ void k_fine(const unsigned* __restrict__ binned, const int* __restrict__ gstart,
                       int* __restrict__ off, int* __restrict__ edges) {
    __shared__ int cnt[BPB];
    __shared__ int tsum[256];
    int b = blockIdx.x, t = threadIdx.x;
    cnt[t] = 0; cnt[t + 256] = 0;
    __syncthreads();
    int s = gstart[b], e = gstart[b + 1];
    for (int i = s + t; i < e; i += 256) atomicAdd(&cnt[binned[i] >> 17], 1);
    __syncthreads();
    int v0 = cnt[2 * t], v1 = cnt[2 * t + 1];
    int ps = v0 + v1;
    tsum[t] = ps;
    __syncthreads();
    for (int o = 1; o < 256; o <<= 1) {
        int x = (t >= o) ? tsum[t - o] : 0;
        __syncthreads();
        tsum[t] += x;
        __syncthreads();
    }
    int base = s + tsum[t] - ps;
    int g0 = b * BPB + 2 * t;
    if (g0 < NSCAN) off[g0] = base;
    if (g0 + 1 < NSCAN) off[g0 + 1] = base + v0;
    __syncthreads();
    cnt[2 * t] = base;
    cnt[2 * t + 1] = base + v0;
    __syncthreads();
    for (int i = s + t; i < e; i += 256) {
        unsigned v = binned[i];
        int pos = atomicAdd(&cnt[v >> 17], 1);
        edges[pos] = (int)(v & 0x1FFFFu);
    }
}

// ===========================================================================
// Gather core: 16 lanes/row, uint4 (8 bf16) per lane, 8-wide load batching.
// ===========================================================================
__device__ __forceinline__ void gacc16(const uint4* __restrict__ feat,
                                       const int* __restrict__ edges,
                                       int start, int end, int c,
                                       float& a0, float& a1, float& a2, float& a3,
                                       float& a4, float& a5, float& a6, float& a7) {
    for (int base = start; base < end; base += 16) {
        int n = end - base; if (n > 16) n = 16;
        int eidx = (c < n) ? edges[base + c] : 0;
        int k = 0;
        for (; k + 8 <= n; k += 8) {
            int s0 = __shfl(eidx, k + 0, 16), s1 = __shfl(eidx, k + 1, 16);
            int s2 = __shfl(eidx, k + 2, 16), s3 = __shfl(eidx, k + 3, 16);
            int s4 = __shfl(eidx, k + 4, 16), s5 = __shfl(eidx, k + 5, 16);
            int s6 = __shfl(eidx, k + 6, 16), s7 = __shfl(eidx, k + 7, 16);
            uint4 p0 = feat[(size_t)s0 * 16 + c], p1 = feat[(size_t)s1 * 16 + c];
            uint4 p2 = feat[(size_t)s2 * 16 + c], p3 = feat[(size_t)s3 * 16 + c];
            uint4 p4 = feat[(size_t)s4 * 16 + c], p5 = feat[(size_t)s5 * 16 + c];
            uint4 p6 = feat[(size_t)s6 * 16 + c], p7 = feat[(size_t)s7 * 16 + c];
            bacc(p0.x, a0, a1); bacc(p0.y, a2, a3); bacc(p0.z, a4, a5); bacc(p0.w, a6, a7);
            bacc(p1.x, a0, a1); bacc(p1.y, a2, a3); bacc(p1.z, a4, a5); bacc(p1.w, a6, a7);
            bacc(p2.x, a0, a1); bacc(p2.y, a2, a3); bacc(p2.z, a4, a5); bacc(p2.w, a6, a7);
            bacc(p3.x, a0, a1); bacc(p3.y, a2, a3); bacc(p3.z, a4, a5); bacc(p3.w, a6, a7);
            bacc(p4.x, a0, a1); bacc(p4.y, a2, a3); bacc(p4.z, a4, a5); bacc(p4.w, a6, a7);
            bacc(p5.x, a0, a1); bacc(p5.y, a2, a3); bacc(p5.z, a4, a5); bacc(p5.w, a6, a7);
            bacc(p6.x, a0, a1); bacc(p6.y, a2, a3); bacc(p6.z, a4, a5); bacc(p6.w, a6, a7);
            bacc(p7.x, a0, a1); bacc(p7.y, a2, a3); bacc(p7.z, a4, a5); bacc(p7.w, a6, a7);
        }
        for (; k + 2 <= n; k += 2) {
            int s0 = __shfl(eidx, k + 0, 16), s1 = __shfl(eidx, k + 1, 16);
            uint4 p0 = feat[(size_t)s0 * 16 + c], p1 = feat[(size_t)s1 * 16 + c];
            bacc(p0.x, a0, a1); bacc(p0.y, a2, a3); bacc(p0.z, a4, a5); bacc(p0.w, a6, a7);
            bacc(p1.x, a0, a1); bacc(p1.y, a2, a3); bacc(p1.z, a4, a5); bacc(p1.w, a6, a7);
        }
        if (k < n) {
            int s0 = __shfl(eidx, k, 16);
            uint4 p0 = feat[(size_t)s0 * 16 + c];
            bacc(p0.x, a0, a1); bacc(p0.y, a2, a3); bacc(p0.z, a4, a5); bacc(p0.w, a6, a7);
        }
    }
}

// Merged forward gather over items [0,NI) + tags [NI,NI+NT); bucket id == row.
__global__ void g_fwd(const uint4* __restrict__ feat,
                      const int* __restrict__ off, const int* __restrict__ edges,
                      uint4* __restrict__ rsti_b, uint4* __restrict__ rstt_b,
                      float4* __restrict__ outf) {
    int tid = blockIdx.x * blockDim.x + threadIdx.x;
    int r = tid >> 4;
    int c = tid & 15;
    if (r >= NI + NT) return;
    int start = off[r];
    int end = off[r + 1];
    float a0=0.f,a1=0.f,a2=0.f,a3=0.f,a4=0.f,a5=0.f,a6=0.f,a7=0.f;
    gacc16(feat, edges, start, end, c, a0, a1, a2, a3, a4, a5, a6, a7);
    float inv = 1.0f / fmaxf((float)(end - start), 1.0f);
    a0*=inv; a1*=inv; a2*=inv; a3*=inv; a4*=inv; a5*=inv; a6*=inv; a7*=inv;
    uint4 ob;
    ob.x = bfpack(a0,a1); ob.y = bfpack(a2,a3);
    ob.z = bfpack(a4,a5); ob.w = bfpack(a6,a7);
    if (r < NI) {
        rsti_b[(size_t)r * 16 + c] = ob;
    } else {
        int rt = r - NI;
        rstt_b[(size_t)rt * 16 + c] = ob;
        nts4(&outf[(size_t)rt * 32 + c*2 + 0], a0, a1, a2, a3);
        nts4(&outf[(size_t)rt * 32 + c*2 + 1], a4, a5, a6, a7);
    }
}

// Backward gather over both reverse etypes; rst_* are bf16, normalized.
__global__ void g_bwd(const uint4* __restrict__ rst_i, const uint4* __restrict__ rst_t,
                      const int* __restrict__ off, const int* __restrict__ edges,
                      float4* __restrict__ bsrc) {
    int tid = blockIdx.x * blockDim.x + threadIdx.x;
    int r = tid >> 4;
    int c = tid & 15;
    if (r >= NU) return;
    int s1 = off[B_UUI + r], e1 = off[B_UUI + r + 1];
    int g2 = B_UUT + r;
    int s2 = off[g2], e2 = (g2 + 1 < NSCAN) ? off[g2 + 1] : TOTAL_E;
    float a0=0.f,a1=0.f,a2=0.f,a3=0.f,a4=0.f,a5=0.f,a6=0.f,a7=0.f;
    gacc16(rst_i, edges, s1, e1, c, a0, a1, a2, a3, a4, a5, a6, a7);
    gacc16(rst_t, edges, s2, e2, c, a0, a1, a2, a3, a4, a5, a6, a7);
    float inv = 1.0f / (fmaxf((float)(e1 - s1), 1.0f) + fmaxf((float)(e2 - s2), 1.0f));
    nts4(&bsrc[(size_t)r * 32 + c*2 + 0], a0*inv, a1*inv, a2*inv, a3*inv);
    nts4(&bsrc[(size_t)r * 32 + c*2 + 1], a4*inv, a5*inv, a6*inv, a7*inv);
}

// ===========================================================================
// Legacy kernels for fallback tiers (unchanged)
// ===========================================================================
__global__ void k_scanA(int* __restrict__ data, int* __restrict__ bsums, int n) {
    __shared__ int lds[256];
    int b = blockIdx.x, t = threadIdx.x;
    int base = b * 1024 + t * 4;
    int v0 = (base + 0 < n) ? data[base + 0] : 0;
    int v1 = (base + 1 < n) ? data[base + 1] : 0;
    int v2 = (base + 2 < n) ? data[base + 2] : 0;
    int v3 = (base + 3 < n) ? data[base + 3] : 0;
    int i0 = v0, i1 = i0 + v1, i2 = i1 + v2, i3 = i2 + v3;
    lds[t] = i3;
    __syncthreads();
    for (int o = 1; o < 256; o <<= 1) {
        int x = (t >= o) ? lds[t - o] : 0;
        __syncthreads();
        lds[t] += x;
        __syncthreads();
    }
    int ex = lds[t] - i3;
    if (base + 0 < n) data[base + 0] = ex + i0;
    if (base + 1 < n) data[base + 1] = ex + i1;
    if (base + 2 < n) data[base + 2] = ex + i2;
    if (base + 3 < n) data[base + 3] = ex + i3;
    if (t == 255) bsums[b] = lds[255];
}

__global__ void k_scanB(int* __restrict__ bsums, int nsb) {
    __shared__ int lds[512];
    int t = threadIdx.x;
    int a = (t < nsb) ? bsums[t] : 0;
    int b2 = (t + 256 < nsb) ? bsums[t + 256] : 0;
    lds[t] = a;
    lds[t + 256] = b2;
    __syncthreads();
    for (int o = 1; o < 512; o <<= 1) {
        int x0 = (t >= o) ? lds[t - o] : 0;
        int x1 = (t + 256 >= o) ? lds[t + 256 - o] : 0;
        __syncthreads();
        lds[t] += x0;
        lds[t + 256] += x1;
        __syncthreads();
    }
    if (t < nsb) bsums[t] = lds[t] - a;
    if (t + 256 < nsb) bsums[t + 256] = lds[t + 256] - b2;
}

__global__ void k_scanC(int* __restrict__ data, const int* __restrict__ bsums, int n) {
    int b = blockIdx.x;
    int add = bsums[b];
    int base = b * 1024 + threadIdx.x * 4;
    if (base + 0 < n) data[base + 0] += add;
    if (base + 1 < n) data[base + 1] += add;
    if (base + 2 < n) data[base + 2] += add;
    if (base + 3 < n) data[base + 3] += add;
}

__global__ void k_count_old(const int4* __restrict__ ui_src, const int4* __restrict__ ui_dst,
                            const int4* __restrict__ ut_src, const int4* __restrict__ ut_dst,
                            int* __restrict__ off) {
    int i = blockIdx.x * blockDim.x + threadIdx.x;
    if (i < EUI / 4) {
        int4 s = ui_src[i], d = ui_dst[i];
        atomicAdd(&off[B_I + d.x], 1); atomicAdd(&off[B_I + d.y], 1);
        atomicAdd(&off[B_I + d.z], 1); atomicAdd(&off[B_I + d.w], 1);
        atomicAdd(&off[B_UUI + s.x], 1); atomicAdd(&off[B_UUI + s.y], 1);
        atomicAdd(&off[B_UUI + s.z], 1); atomicAdd(&off[B_UUI + s.w], 1);
    } else if (i < EUI / 4 + EUT / 4) {
        int j = i - EUI / 4;
        int4 s = ut_src[j], d = ut_dst[j];
        atomicAdd(&off[B_T + d.x], 1); atomicAdd(&off[B_T + d.y], 1);
        atomicAdd(&off[B_T + d.z], 1); atomicAdd(&off[B_T + d.w], 1);
        atomicAdd(&off[B_UUT + s.x], 1); atomicAdd(&off[B_UUT + s.y], 1);
        atomicAdd(&off[B_UUT + s.z], 1); atomicAdd(&off[B_UUT + s.w], 1);
    }
}

__global__ void k_fill_old(const int2* __restrict__ ui_src, const int2* __restrict__ ui_dst,
                           const int2* __restrict__ ut_src, const int2* __restrict__ ut_dst,
                           int* __restrict__ off, int* __restrict__ edges) {
    int i = blockIdx.x * blockDim.x + threadIdx.x;
    if (i < EUI / 2) {
        int2 s = ui_src[i], d = ui_dst[i];
        edges[atomicAdd(&off[B_I + d.x], -1) - 1] = s.x;
        edges[atomicAdd(&off[B_UUI + s.x], -1) - 1] = d.x;
        edges[atomicAdd(&off[B_I + d.y], -1) - 1] = s.y;
        edges[atomicAdd(&off[B_UUI + s.y], -1) - 1] = d.y;
    } else if (i < EUI / 2 + EUT / 2) {
        int j = i - EUI / 2;
        int2 s = ut_src[j], d = ut_dst[j];
        edges[atomicAdd(&off[B_T + d.x], -1) - 1] = s.x;
        edges[atomicAdd(&off[B_UUT + s.x], -1) - 1] = d.x;
        edges[atomicAdd(&off[B_T + d.y], -1) - 1] = s.y;
        edges[atomicAdd(&off[B_UUT + s.y], -1) - 1] = d.y;
    }
}

__global__ void k_gather_fwd_f(const float4* __restrict__ feat,
                               const int* __restrict__ off, const int* __restrict__ edges,
                               uint2* __restrict__ outb, float4* __restrict__ outf,
                               int base, int nrows) {
    int tid = blockIdx.x * blockDim.x + threadIdx.x;
    int r = tid >> 5;
    int c = tid & 31;
    if (r >= nrows) return;
    int g = base + r;
    int start = off[g];
    int end = (g + 1 < NSCAN) ? off[g + 1] : TOTAL_E;
    float a0 = 0.f, a1 = 0.f, a2 = 0.f, a3 = 0.f;
    for (int e = start; e < end; ++e) {
        float4 v = feat[(size_t)edges[e] * 32 + c];
        a0 += v.x; a1 += v.y; a2 += v.z; a3 += v.w;
    }
    float inv = 1.0f / fmaxf((float)(end - start), 1.0f);
    a0 *= inv; a1 *= inv; a2 *= inv; a3 *= inv;
    uint2 ob; ob.x = bfpack(a0, a1); ob.y = bfpack(a2, a3);
    outb[(size_t)r * 32 + c] = ob;
    if (outf) {
        float4 of; of.x = a0; of.y = a1; of.z = a2; of.w = a3;
        outf[(size_t)r * 32 + c] = of;
    }
}

__global__ void k_gather_bwd_b(const uint2* __restrict__ rst_i,
                               const uint2* __restrict__ rst_t,
                               const int* __restrict__ off, const int* __restrict__ edges,
                               float4* __restrict__ bsrc) {
    int tid = blockIdx.x * blockDim.x + threadIdx.x;
    int r = tid >> 5;
    int c = tid & 31;
    if (r >= NU) return;
    int g1 = B_UUI + r;
    int s1 = off[g1], e1 = off[g1 + 1];
    int g2 = B_UUT + r;
    int s2 = off[g2], e2 = (g2 + 1 < NSCAN) ? off[g2 + 1] : TOTAL_E;
    float a0 = 0.f, a1 = 0.f, a2 = 0.f, a3 = 0.f;
    for (int e = s1; e < e1; ++e) {
        uint2 p = rst_i[(size_t)edges[e] * 32 + c];
        bacc(p.x, a0, a1); bacc(p.y, a2, a3);
    }
    for (int e = s2; e < e2; ++e) {
        uint2 p = rst_t[(size_t)edges[e] * 32 + c];
        bacc(p.x, a0, a1); bacc(p.y, a2, a3);
    }
    float inv = 1.0f / (fmaxf((float)(e1 - s1), 1.0f) + fmaxf((float)(e2 - s2), 1.0f));
    float4 o;
    o.x = a0 * inv; o.y = a1 * inv; o.z = a2 * inv; o.w = a3 * inv;
    bsrc[(size_t)r * 32 + c] = o;
}

__global__ void f_count(const int* __restrict__ ui_src, const int* __restrict__ ui_dst,
                        const int* __restrict__ ut_src, const int* __restrict__ ut_dst,
                        float* __restrict__ cnt_uui, float* __restrict__ cnt_i,
                        float* __restrict__ cnt_uut, float* __restrict__ cnt_t) {
    int i = blockIdx.x * blockDim.x + threadIdx.x;
    if (i < EUI) {
        unsafeAtomicAdd(&cnt_uui[ui_src[i]], 1.0f);
        unsafeAtomicAdd(&cnt_i[ui_dst[i]], 1.0f);
    } else if (i < EUI + EUT) {
        int j = i - EUI;
        unsafeAtomicAdd(&cnt_uut[ut_src[j]], 1.0f);
        unsafeAtomicAdd(&cnt_t[ut_dst[j]], 1.0f);
    }
}
__global__ void f_scatter_fwd(const float4* __restrict__ feat, const int* __restrict__ src,
                              const int* __restrict__ dst, float* __restrict__ out_sum, int nedge) {
    int tid = blockIdx.x * blockDim.x + threadIdx.x;
    int e = tid >> 5, c = tid & 31;
    if (e >= nedge) return;
    float4 v = feat[(size_t)src[e] * 32 + c];
    float* o = out_sum + (size_t)dst[e] * DD + c * 4;
    unsafeAtomicAdd(o + 0, v.x); unsafeAtomicAdd(o + 1, v.y);
    unsafeAtomicAdd(o + 2, v.z); unsafeAtomicAdd(o + 3, v.w);
}
__global__ void f_scatter_bwd(const float4* __restrict__ rst_sum, const float* __restrict__ cnt,
                              const int* __restrict__ src, const int* __restrict__ dst,
                              float* __restrict__ bsrc, int nedge) {
    int tid = blockIdx.x * blockDim.x + threadIdx.x;
    int e = tid >> 5, c = tid & 31;
    if (e >= nedge) return;
    float inv = 1.0f / fmaxf(cnt[dst[e]], 1.0f);
    float4 v = rst_sum[(size_t)dst[e] * 32 + c];
    float* o = bsrc + (size_t)src[e] * DD + c * 4;
    unsafeAtomicAdd(o + 0, v.x * inv); unsafeAtomicAdd(o + 1, v.y * inv);
    unsafeAtomicAdd(o + 2, v.z * inv); unsafeAtomicAdd(o + 3, v.w * inv);
}
__global__ void f_norm(float4* __restrict__ rst, const float* __restrict__ cnt, int nrows) {
    int tid = blockIdx.x * blockDim.x + threadIdx.x;
    int r = tid >> 5, c = tid & 31;
    if (r >= nrows) return;
    float inv = 1.0f / fmaxf(cnt[r], 1.0f);
    float4 v = rst[(size_t)r * 32 + c];
    v.x *= inv; v.y *= inv; v.z *= inv; v.w *= inv;
    rst[(size_t)r * 32 + c] = v;
}
__global__ void f_final(float4* __restrict__ bsrc, const float* __restrict__ cnt_a,
                        const float* __restrict__ cnt_b, int nrows) {
    int tid = blockIdx.x * blockDim.x + threadIdx.x;
    int r = tid >> 5, c = tid & 31;
    if (r >= nrows) return;
    float inv = 1.0f / (fmaxf(cnt_a[r], 1.0f) + fmaxf(cnt_b[r], 1.0f));
    float4 v = bsrc[(size_t)r * 32 + c];
    v.x *= inv; v.y *= inv; v.z *= inv; v.w *= inv;
    bsrc[(size_t)r * 32 + c] = v;
}

// ===========================================================================

extern "C" void kernel_launch(void* const* d_in, const int* in_sizes, int n_in,
                              void* d_out, int out_size, void* d_ws, size_t ws_size,
                              hipStream_t stream) {
    const float* h_u  = (const float*)d_in[0];
    const int* ui_src = (const int*)d_in[3];
    const int* ui_dst = (const int*)d_in[4];
    const int* ut_src = (const int*)d_in[5];
    const int* ut_dst = (const int*)d_in[6];

    float* bsrc  = (float*)d_out;                       // [NU*DD]
    float* rst_t = (float*)d_out + (size_t)NU * DD;     // [NT*DD]

    const int B = 256;

    // Workspace layout (NEED_FULL identical to rounds 2-9 -> proven available):
    //   ints : off[NSCAN] | bsums[512] | edges[TOTAL_E]           = 7,482,048 B
    //   bf16 : hu_b[NU*DD] | rsti_b[NI*DD] | rstt_b[NT*DD]        = 43,520,000 B
    // Aliases (dead before their region is written by the gathers):
    //   binned (TOTAL_E u32 = 6.4 MB)            @ rsti_b region
    //   gbin[528]|gstart[529]|cursor[528] ints   @ rstt_b region
    const size_t INT_WORDS = (size_t)NSCAN + 512 + TOTAL_E;    // 1,870,512
    const size_t BASE_B    = INT_WORDS * 4;                    // 7,482,048 (16B-aligned)
    const size_t HUB_B     = (size_t)NU * DD * 2;              // 25,600,000
    const size_t RIB_B     = (size_t)NI * DD * 2;              // 12,800,000
    const size_t RTB_B     = (size_t)NT * DD * 2;              //  5,120,000
    const size_t NEED_FULL = BASE_B + HUB_B + RIB_B + RTB_B;   // 51,002,048
    const size_t NEED_HALF = BASE_B + RIB_B + RTB_B;           // ~25.4 MB

    if (ws_size >= NEED_FULL) {
        int* off      = (int*)d_ws;
        int* bsums    = off + NSCAN;   (void)bsums;
        int* edges    = bsums + 512;
        uint4* hu_b   = (uint4*)((char*)d_ws + BASE_B);
        uint4* rsti_b = (uint4*)((char*)d_ws + BASE_B + HUB_B);
        uint4* rstt_b = (uint4*)((char*)d_ws + BASE_B + HUB_B + RIB_B);
        unsigned* binned = (unsigned*)rsti_b;        // alias, dead before g_fwd writes
        int* gbin   = (int*)rstt_b;                  // alias, dead before g_fwd writes
        int* gstart = gbin + NB;                     // [NB+1]
        int* cursor = gstart + NB + 1;               // [NB]

        // 0. zero the 528 coarse-bin counters
        hipMemsetAsync(gbin, 0, NB * sizeof(int), stream);

        // 1. fused cvt (3125 blocks) + coarse histogram (782 blocks)
        k_cvthist<<<NCVT + NBLK, B, 0, stream>>>(
            (const float4*)h_u, hu_b, ui_src, ui_dst, ut_src, ut_dst, gbin);

        // 2. single-block scan of 528 -> gstart / cursor
        k_scan528<<<1, B, 0, stream>>>(gbin, gstart, cursor);

        // 3. scatter entries into coarse bins (per-block chunk reservation)
        k_scatterbin2<<<NBLK, B, 0, stream>>>(ui_src, ui_dst, ut_src, ut_dst, cursor, binned);

        // 4. fused per-bin count + LDS scan + off write + fine scatter
        k_fine<<<NB, B, 0, stream>>>(binned, gstart, off, edges);

        // 5. merged forward gather (items + tags), then backward gather
        g_fwd<<<((long)(NI + NT) * 16 + B - 1) / B, B, 0, stream>>>(
            hu_b, off, edges, rsti_b, rstt_b, (float4*)rst_t);
        g_bwd<<<((long)NU * 16 + B - 1) / B, B, 0, stream>>>(
            rsti_b, rstt_b, off, edges, (float4*)bsrc);
    } else if (ws_size >= NEED_HALF) {
        int* off   = (int*)d_ws;
        int* bsums = off + NSCAN;
        int* edges = bsums + 512;
        uint2* rsti_b = (uint2*)((char*)d_ws + BASE_B);
        uint2* rstt_b = (uint2*)((char*)d_ws + BASE_B + RIB_B);

        hipMemsetAsync(off, 0, (NSCAN + 512) * sizeof(int), stream);

        int nq = EUI / 4 + EUT / 4;
        k_count_old<<<(nq + B - 1) / B, B, 0, stream>>>(
            (const int4*)ui_src, (const int4*)ui_dst,
            (const int4*)ut_src, (const int4*)ut_dst, off);
        {
            int nblk = (NSCAN + 1023) / 1024;
            k_scanA<<<nblk, B, 0, stream>>>(off, bsums, NSCAN);
            k_scanB<<<1, B, 0, stream>>>(bsums, nblk);
            k_scanC<<<nblk, B, 0, stream>>>(off, bsums, NSCAN);
        }
        int nh = EUI / 2 + EUT / 2;
        k_fill_old<<<(nh + B - 1) / B, B, 0, stream>>>(
            (const int2*)ui_src, (const int2*)ui_dst,
            (const int2*)ut_src, (const int2*)ut_dst, off, edges);

        k_gather_fwd_f<<<((long)NI * 32 + B - 1) / B, B, 0, stream>>>(
            (const float4*)h_u, off, edges, rsti_b, (float4*)nullptr, B_I, NI);
        k_gather_fwd_f<<<((long)NT * 32 + B - 1) / B, B, 0, stream>>>(
            (const float4*)h_u, off, edges, rstt_b, (float4*)rst_t, B_T, NT);
        k_gather_bwd_b<<<((long)NU * 32 + B - 1) / B, B, 0, stream>>>(
            rsti_b, rstt_b, off, edges, (float4*)bsrc);
    } else {
        // Atomic fallback (~26.7 MB ws).
        float* ws        = (float*)d_ws;
        float* rst_i_sum = ws;
        float* cnt_i     = rst_i_sum + (size_t)NI * DD;
        float* cnt_t     = cnt_i + NI;
        float* cnt_uui   = cnt_t + NT;
        float* cnt_uut   = cnt_uui + NU;
        size_t ws_floats = (size_t)NI * DD + NI + NT + NU + NU;

        hipMemsetAsync(d_ws, 0, ws_floats * sizeof(float), stream);
        hipMemsetAsync(d_out, 0, (size_t)out_size * sizeof(float), stream);

        int n = EUI + EUT;
        f_count<<<(n + B - 1) / B, B, 0, stream>>>(ui_src, ui_dst, ut_src, ut_dst,
                                                   cnt_uui, cnt_i, cnt_uut, cnt_t);
        f_scatter_fwd<<<((long)EUI * 32 + B - 1) / B, B, 0, stream>>>(
            (const float4*)h_u, ui_src, ui_dst, rst_i_sum, EUI);
        f_scatter_fwd<<<((long)EUT * 32 + B - 1) / B, B, 0, stream>>>(
            (const float4*)h_u, ut_src, ut_dst, rst_t, EUT);
        f_scatter_bwd<<<((long)EUI * 32 + B - 1) / B, B, 0, stream>>>(
            (const float4*)rst_i_sum, cnt_i, ui_src, ui_dst, bsrc, EUI);
        f_scatter_bwd<<<((long)EUT * 32 + B - 1) / B, B, 0, stream>>>(
            (const float4*)rst_t, cnt_t, ut_src, ut_dst, bsrc, EUT);
        f_norm<<<((long)NT * 32 + B - 1) / B, B, 0, stream>>>((float4*)rst_t, cnt_t, NT);
        f_final<<<((long)NU * 32 + B - 1) / B, B, 0, stream>>>((float4*)bsrc, cnt_uui, cnt_uut, NU);
    }
}